// Round 4
// baseline (232.054 us; speedup 1.0000x reference)
//
#include <hip/hip_runtime.h>

// reconstruction_loss: charbonnier_mean(get_msfa(X,4), get_msfa(Y,4))
// X, Y: [B=8, C=16, H=512, W=512] fp32. Pixel (b,h,w) uses channel
// c = (h%4)*4 + (w%4). Loss = mean over B*H*W of sqrt(d^2 + 1e-6).
//
// Decomposition: plane c=4g+j contributes element j of every float4 in rows
// h == g (mod 4). One work item per (g,j,r,k); grid-stride over batch b.
// Wave reads 64 consecutive float4s (1 KiB stream) per plane -> ideal
// global_load_dwordx4 coalescing; j is wave-uniform (bits 14-15).
//
// Structural HBM floor: every 64B line of used rows is touched (elements at
// stride 16B within the line) -> 4x overfetch is unavoidable:
// 2 arrays * 32 MiB = 64 MiB ~= 11 us @ 6.3 TB/s. Measured dur_us is
// dominated by the harness reset (512 MiB ws poison + 256 MiB input
// restore ~= 200 us fixed), so kernel-side deltas are ~noise.
//
// Fused reduction: block sums atomicAdd (device-scope, fp32) into d_out[0],
// which is zeroed by a graph-capturable hipMemsetAsync. Order
// nondeterminism across 1024 adds ~1e-6 abs -- far under the 2.25e-2
// threshold.

#define EPS_F 1e-6f

constexpr int kBlocks  = 1024;
constexpr int kThreads = 256;
constexpr int kNPix    = 8 * 512 * 512;            // 2097152 pixels
constexpr int kBatchF4 = 16 * 512 * 128;           // float4s per batch = 1<<20

__global__ __launch_bounds__(kThreads) void msfa_charb_fused(
    const float4* __restrict__ X4, const float4* __restrict__ Y4,
    float* __restrict__ out)
{
    const int tid = blockIdx.x * kThreads + threadIdx.x;   // [0, 2^18)
    const int k = tid & 127;          // float4 index within row
    const int r = (tid >> 7) & 127;   // row-within-group
    const int j = (tid >> 14) & 3;    // element to keep (wave-uniform)
    const int g = tid >> 16;          // h-group, 0..3
    const int h = (r << 2) | g;       // h % 4 == g
    const int c = (g << 2) | j;       // channel plane
    const int base = (((c << 9) | h) << 7) | k;            // float4 offset, batch 0

    float acc = 0.0f;
#pragma unroll
    for (int b = 0; b < 8; ++b) {
        const int f = base + b * kBatchF4;
        const float4 x = X4[f];
        const float4 y = Y4[f];
        const float xv = (j == 0) ? x.x : (j == 1) ? x.y : (j == 2) ? x.z : x.w;
        const float yv = (j == 0) ? y.x : (j == 1) ? y.y : (j == 2) ? y.z : y.w;
        const float d = xv - yv;
        acc += sqrtf(d * d + EPS_F);
    }

    // wave64 butterfly reduce
#pragma unroll
    for (int s = 32; s > 0; s >>= 1)
        acc += __shfl_down(acc, s, 64);

    __shared__ float sdata[kThreads / 64];
    const int lane = threadIdx.x & 63;
    const int wave = threadIdx.x >> 6;
    if (lane == 0) sdata[wave] = acc;
    __syncthreads();
    if (threadIdx.x == 0) {
        float t = 0.0f;
#pragma unroll
        for (int i = 0; i < kThreads / 64; ++i) t += sdata[i];
        atomicAdd(out, t * (1.0f / (float)kNPix));  // device-scope by default
    }
}

extern "C" void kernel_launch(void* const* d_in, const int* in_sizes, int n_in,
                              void* d_out, int out_size, void* d_ws, size_t ws_size,
                              hipStream_t stream)
{
    const float4* X4 = (const float4*)d_in[0];
    const float4* Y4 = (const float4*)d_in[1];
    float* out = (float*)d_out;

    hipMemsetAsync(out, 0, sizeof(float), stream);   // capturable; zeroes accumulator
    msfa_charb_fused<<<kBlocks, kThreads, 0, stream>>>(X4, Y4, out);
}